// Round 7
// baseline (3095.622 us; speedup 1.0000x reference)
//
#include <hip/hip_runtime.h>
#include <math.h>

#define BB 64
#define TT 2048
#define II 256
#define HH 256
#define OO 128

typedef __attribute__((ext_vector_type(4))) float f32x4;

// ---------------------------------------------------------------------------
// GEMM with bias: C[m,n] = sum_k A[m,k] * W[n,k] + b1[n] + b2[n]
// (unchanged; only used for xp1)
// ---------------------------------------------------------------------------
template<int N>
__global__ __launch_bounds__(256)
void gemm_bias(const float* __restrict__ A, const float* __restrict__ W,
               const float* __restrict__ b1, const float* __restrict__ b2,
               float* __restrict__ C)
{
    constexpr int K = 256;
    __shared__ float sA[16][132];
    __shared__ float sB[16][132];
    const int tid  = threadIdx.x;
    const long row0 = (long)blockIdx.x * 128;
    const int  col0 = blockIdx.y * 128;

    const int tm = tid & 15;
    const int tn = tid >> 4;

    float acc[8][8];
#pragma unroll
    for (int i = 0; i < 8; ++i)
#pragma unroll
        for (int j = 0; j < 8; ++j) acc[i][j] = 0.f;

    const int f0  = tid;
    const int f1  = tid + 256;
    const int am0 = f0 >> 2, ak0 = (f0 & 3) * 4;
    const int am1 = f1 >> 2, ak1 = (f1 & 3) * 4;

    for (int kt = 0; kt < K; kt += 16) {
        float4 a0 = *(const float4*)&A[(row0 + am0) * K + kt + ak0];
        float4 a1 = *(const float4*)&A[(row0 + am1) * K + kt + ak1];
        float4 w0 = *(const float4*)&W[(long)(col0 + am0) * K + kt + ak0];
        float4 w1 = *(const float4*)&W[(long)(col0 + am1) * K + kt + ak1];
        __syncthreads();
        sA[ak0+0][am0] = a0.x; sA[ak0+1][am0] = a0.y; sA[ak0+2][am0] = a0.z; sA[ak0+3][am0] = a0.w;
        sA[ak1+0][am1] = a1.x; sA[ak1+1][am1] = a1.y; sA[ak1+2][am1] = a1.z; sA[ak1+3][am1] = a1.w;
        sB[ak0+0][am0] = w0.x; sB[ak0+1][am0] = w0.y; sB[ak0+2][am0] = w0.z; sB[ak0+3][am0] = w0.w;
        sB[ak1+0][am1] = w1.x; sB[ak1+1][am1] = w1.y; sB[ak1+2][am1] = w1.z; sB[ak1+3][am1] = w1.w;
        __syncthreads();
#pragma unroll
        for (int k = 0; k < 16; ++k) {
            float4 av0 = *(const float4*)&sA[k][tm * 8];
            float4 av1 = *(const float4*)&sA[k][tm * 8 + 4];
            float4 bv0 = *(const float4*)&sB[k][tn * 8];
            float4 bv1 = *(const float4*)&sB[k][tn * 8 + 4];
            float am[8] = {av0.x, av0.y, av0.z, av0.w, av1.x, av1.y, av1.z, av1.w};
            float bn[8] = {bv0.x, bv0.y, bv0.z, bv0.w, bv1.x, bv1.y, bv1.z, bv1.w};
#pragma unroll
            for (int i = 0; i < 8; ++i)
#pragma unroll
                for (int j = 0; j < 8; ++j)
                    acc[i][j] += am[i] * bn[j];
        }
    }

    float bias[8];
#pragma unroll
    for (int j = 0; j < 8; ++j) {
        int col = col0 + tn * 8 + j;
        bias[j] = b1[col] + b2[col];
    }
#pragma unroll
    for (int i = 0; i < 8; ++i) {
        long row = row0 + tm * 8 + i;
        float4 v0, v1;
        v0.x = acc[i][0] + bias[0]; v0.y = acc[i][1] + bias[1];
        v0.z = acc[i][2] + bias[2]; v0.w = acc[i][3] + bias[3];
        v1.x = acc[i][4] + bias[4]; v1.y = acc[i][5] + bias[5];
        v1.z = acc[i][6] + bias[6]; v1.w = acc[i][7] + bias[7];
        *(float4*)&C[row * N + col0 + tn * 8]     = v0;
        *(float4*)&C[row * N + col0 + tn * 8 + 4] = v1;
    }
}

__device__ __forceinline__ float fast_tanh(float x) {
    float e = __expf(2.f * x);
    return 1.f - 2.f / (e + 1.f);
}

// Light barrier: LDS-ordering only; no vmcnt drain.
#define LIGHT_BARRIER() do {                                       \
    asm volatile("s_waitcnt lgkmcnt(0)" ::: "memory");             \
    __builtin_amdgcn_s_barrier();                                  \
} while (0)

// Keep-alive pin: hoists the one-time weight loads out of the loop.
#define PIN4(v) asm volatile("" : "+v"((v).x), "+v"((v).y), "+v"((v).z), "+v"((v).w))

// Pair-sum x with the lane^32 partner (VALU permlane, no LDS pipe).
#define PAIRSUM(dst_, x_) do {                                         \
    float _t = (x_), _u = (x_);                                        \
    asm("v_permlane32_swap_b32 %0, %1" : "+v"(_t), "+v"(_u));          \
    (dst_) = _t + _u;                                                  \
} while (0)

// ---------------------------------------------------------------------------
// Round-7: TWO independent batch chains per WG (A/B), half-step offset.
// 32 producer WGs + 32 consumer WGs x 512 threads. The two chains share the
// same register-resident weight slice; each barrier interval contains one
// chain's full FMA block overlapped with the other chain's reduce/stage —
// the serial-latency chain of one chain hides under the issue of the other.
// ---------------------------------------------------------------------------
__global__ __launch_bounds__(512, 2)
void rnn_pipe(const float* __restrict__ W_hh1,
              const float* __restrict__ W_ih2,
              const float* __restrict__ W_hh2,
              const float* __restrict__ b_ih2,
              const float* __restrict__ b_hh2,
              float* __restrict__ XH,          // xp1 in / h1 out (in place)
              float* __restrict__ out,         // [B*T, OO]
              int* __restrict__ flags)         // [BB/2], pre-zeroed
{
    const int tid = threadIdx.x;
    const int g   = tid & 31;
    const int ks  = tid >> 5;
    const int kp  = ks >> 1;

    if (blockIdx.x < BB / 2) {
        // ------------------------- producer (2 chains) --------------------
        __shared__ float hA[256], hB[256];
        __shared__ float partA[8 * 256], partB[8 * 256];
        const int pb = blockIdx.x;
        const int bA = 2 * pb, bB = 2 * pb + 1;

        float4 w[8][4];
#pragma unroll
        for (int r = 0; r < 8; ++r)
#pragma unroll
            for (int c = 0; c < 4; ++c)
                w[r][c] = *(const float4*)&W_hh1[(g * 8 + r) * 256 + ks * 16 + c * 4];
#pragma unroll
        for (int r = 0; r < 8; ++r)
#pragma unroll
            for (int c = 0; c < 4; ++c)
                PIN4(w[r][c]);

        float* rowpA = XH + (long)bA * TT * HH;
        float* rowpB = XH + (long)bB * TT * HH;

        float xpbA[8], xpbB[8];
#pragma unroll
        for (int j = 0; j < 8; ++j) { xpbA[j] = 0.f; xpbB[j] = 0.f; }
        if (tid < 256) {
            hA[tid] = 0.f; hB[tid] = 0.f;
#pragma unroll
            for (int j = 0; j < 8; ++j) {
                xpbA[j] = rowpA[(long)j * HH + tid];
                xpbB[j] = rowpB[(long)j * HH + tid];
            }
        }
        // prologue substitute for A-partials(0) with h=0: partA := 0
        *(float4*)&partA[tid * 4] = make_float4(0.f, 0.f, 0.f, 0.f);

        // gather offset: row n = g*8+r lives at (r>=4)*128 + g*4 + (r&3)
        const int ro = ((tid & 7) >> 2) * 128 + ((tid >> 3) << 2) + (tid & 3);

        // chain-X partials: 128 FMA -> pairsum -> 1 b128 LDS write
        auto prod_partials = [&](const float* hbuf, float* pbuf) {
            float a[8];
#pragma unroll
            for (int r = 0; r < 8; ++r) a[r] = 0.f;
#pragma unroll
            for (int c = 0; c < 4; ++c) {
                float4 h4c = *(const float4*)&hbuf[ks * 16 + c * 4];
#pragma unroll
                for (int r = 0; r < 8; ++r)
                    a[r] += w[r][c].x * h4c.x + w[r][c].y * h4c.y
                          + w[r][c].z * h4c.z + w[r][c].w * h4c.w;
            }
            float s[8];
#pragma unroll
            for (int r = 0; r < 8; ++r) PAIRSUM(s[r], a[r]);
            if (!(ks & 1))
                *(float4*)&pbuf[kp * 256 + g * 4] =
                    make_float4(s[0], s[1], s[2], s[3]);
            else
                *(float4*)&pbuf[kp * 256 + 128 + g * 4] =
                    make_float4(s[4], s[5], s[6], s[7]);
        };

        LIGHT_BARRIER();

        for (int t0 = 0; t0 < TT; t0 += 8) {
#pragma unroll
            for (int j = 0; j < 8; ++j) {
                const int t = t0 + j;
                // ---- interval 1: B-partials(t) || A-finish(t) ----
                prod_partials(hB, partB);
                if (tid < 256) {
                    float r0 = partA[0 * 256 + ro] + partA[1 * 256 + ro]
                             + partA[2 * 256 + ro] + partA[3 * 256 + ro];
                    float r1 = partA[4 * 256 + ro] + partA[5 * 256 + ro]
                             + partA[6 * 256 + ro] + partA[7 * 256 + ro];
                    float v = fast_tanh((r0 + r1) + xpbA[j]);
                    hA[tid] = v;
                    rowpA[(long)t * HH + tid] = v;
                }
                LIGHT_BARRIER();
                // ---- interval 2: A-partials(t+1) || B-finish(t) ----
                if (t + 1 < TT) prod_partials(hA, partA);
                if (tid < 256) {
                    float r0 = partB[0 * 256 + ro] + partB[1 * 256 + ro]
                             + partB[2 * 256 + ro] + partB[3 * 256 + ro];
                    float r1 = partB[4 * 256 + ro] + partB[5 * 256 + ro]
                             + partB[6 * 256 + ro] + partB[7 * 256 + ro];
                    float v = fast_tanh((r0 + r1) + xpbB[j]);
                    hB[tid] = v;
                    rowpB[(long)t * HH + tid] = v;
                }
                LIGHT_BARRIER();
            }

            // group tail: drain + publish both chains (one flag per pair)
            asm volatile("s_waitcnt vmcnt(0) lgkmcnt(0)" ::: "memory");
            __builtin_amdgcn_s_barrier();
            if (tid == 0)
                __hip_atomic_store(&flags[pb], t0 + 8, __ATOMIC_RELEASE,
                                   __HIP_MEMORY_SCOPE_AGENT);

            // refill xp prefetch for the next group
            if (tid < 256 && t0 + 8 < TT) {
#pragma unroll
                for (int j = 0; j < 8; ++j) {
                    xpbA[j] = rowpA[(long)(t0 + 8 + j) * HH + tid];
                    xpbB[j] = rowpB[(long)(t0 + 8 + j) * HH + tid];
                }
            }
        }
    } else {
        // ------------------------- consumer (2 chains) --------------------
        __shared__ float h1A[256], h1B[256];
        __shared__ float oA[128], oB[128];
        __shared__ float p2A[8 * 132], p2B[8 * 132];
        __shared__ int   seen_sh;
        const int cb = blockIdx.x - BB / 2;
        const int bA = 2 * cb, bB = 2 * cb + 1;

        float4 wi[4][4];
        float4 wh[4][2];
#pragma unroll
        for (int r = 0; r < 4; ++r) {
#pragma unroll
            for (int c = 0; c < 4; ++c)
                wi[r][c] = *(const float4*)&W_ih2[(g * 4 + r) * 256 + ks * 16 + c * 4];
#pragma unroll
            for (int c = 0; c < 2; ++c)
                wh[r][c] = *(const float4*)&W_hh2[(g * 4 + r) * 128 + ks * 8 + c * 4];
        }
#pragma unroll
        for (int r = 0; r < 4; ++r) {
#pragma unroll
            for (int c = 0; c < 4; ++c) PIN4(wi[r][c]);
#pragma unroll
            for (int c = 0; c < 2; ++c) PIN4(wh[r][c]);
        }

        float bias = 0.f;
        if (tid < 128) {
            bias = b_ih2[tid] + b_hh2[tid];
            oA[tid] = 0.f; oB[tid] = 0.f;
        }
        const float* h1pA = XH + (long)bA * TT * HH;
        const float* h1pB = XH + (long)bB * TT * HH;
        float* outpA = out + (long)bA * TT * OO;
        float* outpB = out + (long)bB * TT * OO;

        // chain-X partials: wi x h1 + wh x o -> pairsum -> b128 write
        auto cons_partials = [&](const float* h1buf, const float* obuf,
                                 float* pbuf) {
            float a2[4];
#pragma unroll
            for (int r = 0; r < 4; ++r) a2[r] = 0.f;
#pragma unroll
            for (int c = 0; c < 4; ++c) {
                float4 h4c = *(const float4*)&h1buf[ks * 16 + c * 4];
#pragma unroll
                for (int r = 0; r < 4; ++r)
                    a2[r] += wi[r][c].x * h4c.x + wi[r][c].y * h4c.y
                           + wi[r][c].z * h4c.z + wi[r][c].w * h4c.w;
            }
#pragma unroll
            for (int c = 0; c < 2; ++c) {
                float4 o4c = *(const float4*)&obuf[ks * 8 + c * 4];
#pragma unroll
                for (int r = 0; r < 4; ++r)
                    a2[r] += wh[r][c].x * o4c.x + wh[r][c].y * o4c.y
                           + wh[r][c].z * o4c.z + wh[r][c].w * o4c.w;
            }
            float s2[4];
#pragma unroll
            for (int r = 0; r < 4; ++r) PAIRSUM(s2[r], a2[r]);
            if (!(ks & 1))
                *(float4*)&pbuf[kp * 132 + g * 4] =
                    make_float4(s2[0], s2[1], s2[2], s2[3]);
        };

        f32x4 pfA = {0.f, 0.f, 0.f, 0.f};
        f32x4 pfB = {0.f, 0.f, 0.f, 0.f};
        LIGHT_BARRIER();

        for (int t0 = 0; t0 < TT; t0 += 8) {
            // group flag wait (producer publishes rows <= t0+7 at flag t0+8)
            if (tid == 0) {
                int s;
                do {
                    s = __hip_atomic_load(&flags[cb], __ATOMIC_RELAXED,
                                          __HIP_MEMORY_SCOPE_AGENT);
                } while (s < t0 + 8);
                s = __hip_atomic_load(&flags[cb], __ATOMIC_ACQUIRE,
                                      __HIP_MEMORY_SCOPE_AGENT);
                seen_sh = s;
            }
            LIGHT_BARRIER();
            (void)seen_sh;

            // group start: stage h1A(t0); preload pfB(t0); issue pfA(t0+1)
            if (tid < 64) {
                f32x4 a0 = *(const f32x4*)&h1pA[(long)t0 * HH + tid * 4];
                pfB = *(const f32x4*)&h1pB[(long)t0 * HH + tid * 4];
                *(f32x4*)&h1A[tid * 4] = a0;
                pfA = *(const f32x4*)&h1pA[(long)(t0 + 1) * HH + tid * 4];
            }
            LIGHT_BARRIER();

#pragma unroll
            for (int j = 0; j < 8; ++j) {
                const int t = t0 + j;
                // -- interval 1: A-compute(t) || B-finish(t-1) || B-stage(t)
                if (tid < 64) {
                    *(f32x4*)&h1B[tid * 4] = pfB;
                    if (j < 7)
                        pfB = *(const f32x4*)&h1pB[(long)(t + 1) * HH + tid * 4];
                }
                cons_partials(h1A, oA, p2A);
                if (t > 0 && tid < 128) {
                    float s = bias;
#pragma unroll
                    for (int st = 0; st < 8; ++st) s += p2B[st * 132 + tid];
                    float v = fast_tanh(s);
                    oB[tid] = v;
                    __builtin_nontemporal_store(v, &outpB[(long)(t - 1) * OO + tid]);
                }
                LIGHT_BARRIER();
                // -- interval 2: B-compute(t) || A-finish(t) || A-stage(t+1)
                if (tid < 64 && j < 7) {
                    *(f32x4*)&h1A[tid * 4] = pfA;
                    if (j < 6)
                        pfA = *(const f32x4*)&h1pA[(long)(t + 2) * HH + tid * 4];
                }
                cons_partials(h1B, oB, p2B);
                if (tid < 128) {
                    float s = bias;
#pragma unroll
                    for (int st = 0; st < 8; ++st) s += p2A[st * 132 + tid];
                    float v = fast_tanh(s);
                    oA[tid] = v;
                    __builtin_nontemporal_store(v, &outpA[(long)t * OO + tid]);
                }
                LIGHT_BARRIER();
            }
        }
        // epilogue: B-finish(TT-1)
        if (tid < 128) {
            float s = bias;
#pragma unroll
            for (int st = 0; st < 8; ++st) s += p2B[st * 132 + tid];
            __builtin_nontemporal_store(fast_tanh(s),
                                        &outpB[(long)(TT - 1) * OO + tid]);
        }
    }
}

// ---------------------------------------------------------------------------
extern "C" void kernel_launch(void* const* d_in, const int* in_sizes, int n_in,
                              void* d_out, int out_size, void* d_ws, size_t ws_size,
                              hipStream_t stream)
{
    const float* x     = (const float*)d_in[0];
    const float* W_ih1 = (const float*)d_in[1];
    const float* W_hh1 = (const float*)d_in[2];
    const float* b_ih1 = (const float*)d_in[3];
    const float* b_hh1 = (const float*)d_in[4];
    const float* W_ih2 = (const float*)d_in[5];
    const float* W_hh2 = (const float*)d_in[6];
    const float* b_ih2 = (const float*)d_in[7];
    const float* b_hh2 = (const float*)d_in[8];
    float* out = (float*)d_out;

    float* xp1 = (float*)d_ws;                         // [B*T, 256] = 128 MiB
    const size_t FLAG_OFF = (size_t)BB * TT * HH * sizeof(float);
    int* flags = (int*)((char*)d_ws + FLAG_OFF);       // [32] ints (per pair)

    const int M = BB * TT;                             // 131072

    (void)hipMemsetAsync(flags, 0, (BB / 2) * sizeof(int), stream);

    // Phase A: xp1 = x @ W_ih1^T + b_ih1 + b_hh1   -> ws
    dim3 gA(M / 128, HH / 128);
    gemm_bias<HH><<<gA, 256, 0, stream>>>(x, W_ih1, b_ih1, b_hh1, xp1);

    // Phase B: 32 producer WGs (2 chains each) + 32 consumer WGs (2 chains)
    rnn_pipe<<<BB, 512, 0, stream>>>(W_hh1, W_ih2, W_hh2, b_ih2, b_hh2,
                                     xp1, out, flags);
}